// Round 1
// 2517.412 us; speedup vs baseline: 2.1530x; 2.1530x over previous
//
#include <hip/hip_runtime.h>
#include <math.h>

// mLSTM block, MI355X round 1: m97-structure bf16 GEMM (global_load_lds, linear LDS).
constexpr int BB = 4096;   // batch
constexpr int DD = 2048;   // input size
constexpr int PP = 4096;   // proj size
constexpr int HH = 4096;   // hidden
constexpr int NH = 16;
constexpr int HS = 256;

using bf16 = __bf16;
typedef __attribute__((ext_vector_type(8))) __bf16 bf16x8;
typedef __attribute__((ext_vector_type(2))) __bf16 bf16x2;
typedef __attribute__((ext_vector_type(4))) float  floatx4;

// ---------------------------------------------------------------- async 16B global->LDS
__device__ __forceinline__ void gl_lds16(const bf16* g, bf16* l) {
    __builtin_amdgcn_global_load_lds(
        (__attribute__((address_space(1))) void*)g,
        (__attribute__((address_space(3))) void*)l,
        16, 0, 0);
}

// ---------------------------------------------------------------- LayerNorm -> bf16
__global__ void ln_kernel(const float* __restrict__ x, const float* __restrict__ g,
                          const float* __restrict__ b, bf16* __restrict__ xn) {
    int row = blockIdx.x;
    int tid = threadIdx.x;
    const float* xr = x + (long)row * DD;
    float v[8];
    float s1 = 0.f, s2 = 0.f;
#pragma unroll
    for (int i = 0; i < 8; ++i) {
        v[i] = xr[tid + 256 * i];
        s1 += v[i]; s2 += v[i] * v[i];
    }
    for (int off = 32; off > 0; off >>= 1) {
        s1 += __shfl_down(s1, off);
        s2 += __shfl_down(s2, off);
    }
    __shared__ float r1[4], r2[4];
    if ((tid & 63) == 0) { r1[tid >> 6] = s1; r2[tid >> 6] = s2; }
    __syncthreads();
    float t1 = r1[0] + r1[1] + r1[2] + r1[3];
    float t2 = r2[0] + r2[1] + r2[2] + r2[3];
    float mu  = t1 * (1.f / DD);
    float var = t2 * (1.f / DD) - mu * mu;
    float inv = rsqrtf(var + 1e-5f);
    bf16* xo = xn + (long)row * DD;
#pragma unroll
    for (int i = 0; i < 8; ++i) {
        int c = tid + 256 * i;
        xo[c] = (bf16)((v[i] - mu) * inv * g[c] + b[c]);
    }
}

// ---------------------------------------------------------------- transpose-convert
// in: [R][C] fp32 row-major  ->  out: [C][R] bf16 row-major.  R%64==0, C%32==0.
__global__ __launch_bounds__(256)
void tconv_kernel(const float* __restrict__ in, bf16* __restrict__ out, int R, int C) {
    __shared__ float t[64][33];
    const long zo = (long)blockIdx.z * (long)R * C;
    in  += zo; out += zo;
    const int c0 = blockIdx.x * 32, r0 = blockIdx.y * 64;
    const int xx = threadIdx.x & 31, yy = threadIdx.x >> 5;   // yy: 0..7
#pragma unroll
    for (int d = 0; d < 64; d += 8)
        t[yy + d][xx] = in[(long)(r0 + yy + d) * C + c0 + xx];
    __syncthreads();
#pragma unroll
    for (int d = 0; d < 32; d += 8) {
        const int cc = c0 + yy + d;
        bf16x2 pk;
        pk.x = (bf16)t[2 * xx + 0][yy + d];
        pk.y = (bf16)t[2 * xx + 1][yy + d];
        *reinterpret_cast<bf16x2*>(&out[(long)cc * R + r0 + 2 * xx]) = pk;
    }
}

// ---------------------------------------------------------------- conv + silu -> bf16
__global__ void conv_silu_kernel(const float* __restrict__ xl, const float* __restrict__ w,
                                 const float* __restrict__ cb, bf16* __restrict__ xc) {
    long i = (long)blockIdx.x * 256 + threadIdx.x;   // over B*P
    int p = (int)(i & (PP - 1));
    const float* base = xl + (i - p);
    float acc = cb[0];
#pragma unroll
    for (int j = 0; j < 4; ++j) {
        int pp = p - 3 + j;
        if (pp >= 0) acc = fmaf(w[j], base[pp], acc);
    }
    xc[i] = (bf16)(acc / (1.f + expf(-acc)));
}

// ---------------------------------------------------------------- gates
__global__ void gates_kernel(const float* __restrict__ it_, const float* __restrict__ ft_,
                             const float* __restrict__ mp, const float* __restrict__ cp,
                             const float* __restrict__ np, const float* __restrict__ kk,
                             const float* __restrict__ vv,
                             float* __restrict__ c_out, float* __restrict__ n_out,
                             float* __restrict__ m_out) {
    long i = (long)blockIdx.x * 256 + threadIdx.x;   // over B*H
    float it = it_[i], ft = ft_[i];
    float fm = ft + mp[i];
    float mt = fmaxf(fm, it);
    float ig = expf(it - mt);
    float fg = expf(fm - mt);
    float ks = kk[i] * 0.0625f;                       // 1/sqrt(HS)
    c_out[i] = fg * cp[i] + ig * (vv[i] * ks);
    n_out[i] = fg * np[i] + ig * ks;
    m_out[i] = mt;
}

// ---------------------------------------------------------------- h_t + GroupNorm + mix
__global__ void hgn_kernel(const float* __restrict__ o_pre, const float* __restrict__ ct,
                           const float* __restrict__ qm, const float* __restrict__ den,
                           const float* __restrict__ xs, const float* __restrict__ xr,
                           const float* __restrict__ gg, const float* __restrict__ gb,
                           float* __restrict__ h_out, bf16* __restrict__ s_out) {
    int blk = blockIdx.x;            // b*NH + head
    int b = blk >> 4, hd = blk & 15;
    int c = threadIdx.x;             // 0..255 == HS
    int gcol = hd * HS + c;
    long idx = (long)b * HH + gcol;
    float o  = 1.f / (1.f + expf(-o_pre[idx]));
    float ht = o * ct[idx] * qm[idx] / fmaxf(fabsf(den[idx]), 1.f);
    h_out[idx] = ht;
    float s1 = ht, s2 = ht * ht;
    for (int off = 32; off > 0; off >>= 1) {
        s1 += __shfl_down(s1, off);
        s2 += __shfl_down(s2, off);
    }
    __shared__ float r1[4], r2[4];
    if ((c & 63) == 0) { r1[c >> 6] = s1; r2[c >> 6] = s2; }
    __syncthreads();
    float t1 = r1[0] + r1[1] + r1[2] + r1[3];
    float t2 = r2[0] + r2[1] + r2[2] + r2[3];
    float mu  = t1 * (1.f / HS);
    float var = t2 * (1.f / HS) - mu * mu;
    float gn  = (ht - mu) * rsqrtf(var + 1e-5f) * gg[gcol] + gb[gcol];
    float xrv = xr[idx];
    float sil = xrv / (1.f + expf(-xrv));
    s_out[idx] = (bf16)((gn + xs[idx]) * sil);
}

// ---------------------------------------------------------------- GEMM (m97 structure)
// C[m,n] = sum_k A[m,k] * Bt[n,k] + bias[n] (+ res). A:[M,K] bf16, Bt:[N,K] bf16.
// 128x128 tile, BK=32, 256 threads = 4 waves (2x2 of 64x64), mfma_f32_16x16x32_bf16.
// Staging: global_load_lds dwordx4 into linear LDS [row][32] (no pad).
template<bool WRITE_BF16, bool ADD_RES>
__global__ __launch_bounds__(256)
void gemm_nt(const bf16* __restrict__ A, int lda, long sAz,
             const bf16* __restrict__ Bt, int ldb, long sBz,
             const float* __restrict__ bias, int sbz,
             const float* __restrict__ res,
             float* __restrict__ C, int ldc, long sCz,
             bf16* __restrict__ Cb, int ldcb, long sCbz,
             int K) {
    __shared__ bf16 As[128 * 32];
    __shared__ bf16 Bs[128 * 32];
    const int tid = threadIdx.x;
    const int m0 = blockIdx.y * 128, n0 = blockIdx.x * 128, z = blockIdx.z;
    A  += (long)z * sAz;
    Bt += (long)z * sBz;
    C  += (long)z * sCz;
    if (bias) bias += (long)z * sbz;
    if (WRITE_BF16) Cb += (long)z * sCbz;

    const int lane = tid & 63, wave = tid >> 6;
    const int row = tid >> 2;            // 0..63 (16 rows per wave)
    const int kc  = (tid & 3) * 8;       // bf16 offset along k
    const bf16* ga = A  + (long)(m0 + row) * lda + kc;
    const bf16* gb = Bt + (long)(n0 + row) * ldb + kc;
    bf16* lA = As + wave * (16 * 32);    // wave-uniform LDS base; lane*16B implicit
    bf16* lB = Bs + wave * (16 * 32);
    const long stepA = (long)64 * lda, stepB = (long)64 * ldb;

    const int wm = (wave >> 1) * 64, wn = (wave & 1) * 64;
    const int lr = lane & 15, qd = lane >> 4;
    floatx4 acc[4][4] = {};

    for (int k0 = 0; k0 < K; k0 += 32) {
        gl_lds16(ga,         lA);
        gl_lds16(ga + stepA, lA + 64 * 32);
        gl_lds16(gb,         lB);
        gl_lds16(gb + stepB, lB + 64 * 32);
        ga += 32; gb += 32;
        __syncthreads();                 // compiler drains vmcnt before barrier

        bf16x8 af[4], bfv[4];
#pragma unroll
        for (int i = 0; i < 4; ++i)
            af[i]  = *reinterpret_cast<const bf16x8*>(&As[(wm + i * 16 + lr) * 32 + qd * 8]);
#pragma unroll
        for (int j = 0; j < 4; ++j)
            bfv[j] = *reinterpret_cast<const bf16x8*>(&Bs[(wn + j * 16 + lr) * 32 + qd * 8]);
#pragma unroll
        for (int i = 0; i < 4; ++i)
#pragma unroll
            for (int j = 0; j < 4; ++j)
                acc[i][j] = __builtin_amdgcn_mfma_f32_16x16x32_bf16(af[i], bfv[j], acc[i][j], 0, 0, 0);
        __syncthreads();
    }

    // epilogue: D row = qd*4 + r, col = lr (verified m89 layout)
#pragma unroll
    for (int i = 0; i < 4; ++i) {
        const int rowb = m0 + wm + i * 16 + qd * 4;
#pragma unroll
        for (int j = 0; j < 4; ++j) {
            const int col = n0 + wn + j * 16 + lr;
            const float bi = bias ? bias[col] : 0.f;
#pragma unroll
            for (int r = 0; r < 4; ++r) {
                const long gi = (long)(rowb + r) * ldc + col;
                float v0 = acc[i][j][r] + bi;
                if (ADD_RES) v0 += res[gi];
                C[gi] = v0;
                if (WRITE_BF16) Cb[(long)(rowb + r) * ldcb + col] = (bf16)v0;
            }
        }
    }
}

// ---------------------------------------------------------------- launch
extern "C" void kernel_launch(void* const* d_in, const int* in_sizes, int n_in,
                              void* d_out, int out_size, void* d_ws, size_t ws_size,
                              hipStream_t stream) {
    const float* x      = (const float*)d_in[0];
    // d_in[1] = h_prev (unused by the reference math)
    const float* c_prev = (const float*)d_in[2];
    const float* n_prev = (const float*)d_in[3];
    const float* m_prev = (const float*)d_in[4];
    const float* ln_g   = (const float*)d_in[5];
    const float* ln_b   = (const float*)d_in[6];
    const float* W_upL  = (const float*)d_in[7];
    const float* b_upL  = (const float*)d_in[8];
    const float* W_upR  = (const float*)d_in[9];
    const float* b_upR  = (const float*)d_in[10];
    const float* conv_w = (const float*)d_in[11];
    const float* conv_b = (const float*)d_in[12];
    const float* W_skip = (const float*)d_in[13];
    const float* b_skip = (const float*)d_in[14];
    const float* Wq_w   = (const float*)d_in[15];
    const float* Wq_b   = (const float*)d_in[16];
    const float* Wk_w   = (const float*)d_in[17];
    const float* Wk_b   = (const float*)d_in[18];
    const float* Wv_w   = (const float*)d_in[19];
    const float* Wv_b   = (const float*)d_in[20];
    const float* Wi_w   = (const float*)d_in[21];
    const float* Wi_b   = (const float*)d_in[22];
    const float* Wf_w   = (const float*)d_in[23];
    const float* Wf_b   = (const float*)d_in[24];
    const float* Wo_w   = (const float*)d_in[25];
    const float* Wo_b   = (const float*)d_in[26];
    const float* gn_g   = (const float*)d_in[27];
    const float* gn_b   = (const float*)d_in[28];
    const float* W_down = (const float*)d_in[29];
    const float* b_down = (const float*)d_in[30];

    float* out0  = (float*)d_out;                       // [B, D]
    float* h_out = out0  + (long)BB * DD;               // [B, H]
    float* c_out = h_out + (long)BB * HH;
    float* n_out = c_out + (long)BB * HH;
    float* m_out = n_out + (long)BB * HH;

    // Workspace: 9 fp32 slots of B*H floats (64 MiB) = 576 MiB, lifetime-aliased.
    float* ws = (float*)d_ws;
    const long SLOT = (long)BB * HH;                    // 16,777,216 floats
    float* s0 = ws + 0 * SLOT;   // xr fp32                         [live -> hgn]
    float* s1 = ws + 1 * SLOT;   // xs fp32                         [-> hgn]
    float* s2 = ws + 2 * SLOT;   // it fp32 [-> gates], then denom  [-> hgn]
    float* s3 = ws + 3 * SLOT;   // ft fp32 [-> gates], then nT_bf | qT_bf
    float* s4 = ws + 4 * SLOT;   // opre fp32                       [-> hgn]
    float* s5 = ws + 5 * SLOT;   // q fp32                          [-> hgn]
    float* s6 = ws + 6 * SLOT;   // xn_bf + xl_bf, then k fp32      [-> gates]
    float* s7 = ws + 7 * SLOT;   // xl fp32 [-> conv], then v fp32 [-> gates], then s_bf
    float* s8 = ws + 8 * SLOT;   // wt scratch (32MB) + xc_bf (32MB)

    float* xr   = s0;
    float* xs   = s1;
    float* it   = s2;
    float* den  = s2;
    float* ft   = s3;
    float* opre = s4;
    float* qbuf = s5;
    float* kbuf = s6;
    float* xl   = s7;
    float* vbuf = s7;

    bf16* xn_bf = (bf16*)s6;                 // 16 MB  [ln .. upR]
    bf16* xl_bf = (bf16*)(s6 + SLOT / 4);    // 32 MB  [upL .. v-gemm]
    bf16* nT_bf = (bf16*)s3;                 // 32 MB  [after gates]
    bf16* qT_bf = (bf16*)(s3 + SLOT / 2);    // 32 MB
    bf16* wt    = (bf16*)s8;                 // 32 MB weight scratch (per-GEMM)
    bf16* xc_bf = (bf16*)(s8 + SLOT / 2);    // 32 MB  [conv .. k-gemm]
    bf16* s_bf  = (bf16*)s7;                 // 32 MB  [hgn .. down]

    dim3 blk(256);

    // 1. LayerNorm -> bf16
    ln_kernel<<<BB, blk, 0, stream>>>(x, ln_g, ln_b, xn_bf);

    // 2. x_left = xn @ W_upL + b_upL  (fp32 for conv, bf16 for v/o GEMMs)
    tconv_kernel<<<dim3(PP / 32, DD / 64, 1), blk, 0, stream>>>(W_upL, wt, DD, PP);
    gemm_nt<true, false><<<dim3(PP / 128, BB / 128, 1), blk, 0, stream>>>(
        xn_bf, DD, 0, wt, DD, 0, b_upL, 0, nullptr, xl, PP, 0, xl_bf, PP, 0, DD);

    // 3. x_right = xn @ W_upR + b_upR (fp32, consumed elementwise in hgn)
    tconv_kernel<<<dim3(HH / 32, DD / 64, 1), blk, 0, stream>>>(W_upR, wt, DD, HH);
    gemm_nt<false, false><<<dim3(HH / 128, BB / 128, 1), blk, 0, stream>>>(
        xn_bf, DD, 0, wt, DD, 0, b_upR, 0, nullptr, xr, HH, 0, nullptr, 0, 0, DD);

    // 4. causal conv(4) + silu -> bf16
    conv_silu_kernel<<<dim3((unsigned)((long)BB * PP / 256)), blk, 0, stream>>>(
        xl, conv_w, conv_b, xc_bf);

    // 5. x_skip = xc @ W_skip
    tconv_kernel<<<dim3(HH / 32, PP / 64, 1), blk, 0, stream>>>(W_skip, wt, PP, HH);
    gemm_nt<false, false><<<dim3(HH / 128, BB / 128, 1), blk, 0, stream>>>(
        xc_bf, PP, 0, wt, PP, 0, b_skip, 0, nullptr, xs, HH, 0, nullptr, 0, 0, PP);

    // 6. i_tilde = xc @ Wi
    tconv_kernel<<<dim3(HH / 32, PP / 64, 1), blk, 0, stream>>>(Wi_w, wt, PP, HH);
    gemm_nt<false, false><<<dim3(HH / 128, BB / 128, 1), blk, 0, stream>>>(
        xc_bf, PP, 0, wt, PP, 0, Wi_b, 0, nullptr, it, HH, 0, nullptr, 0, 0, PP);

    // 7. f_tilde = xc @ Wf
    tconv_kernel<<<dim3(HH / 32, PP / 64, 1), blk, 0, stream>>>(Wf_w, wt, PP, HH);
    gemm_nt<false, false><<<dim3(HH / 128, BB / 128, 1), blk, 0, stream>>>(
        xc_bf, PP, 0, wt, PP, 0, Wf_b, 0, nullptr, ft, HH, 0, nullptr, 0, 0, PP);

    // 8. o_pre = xl @ Wo
    tconv_kernel<<<dim3(HH / 32, PP / 64, 1), blk, 0, stream>>>(Wo_w, wt, PP, HH);
    gemm_nt<false, false><<<dim3(HH / 128, BB / 128, 1), blk, 0, stream>>>(
        xl_bf, PP, 0, wt, PP, 0, Wo_b, 0, nullptr, opre, HH, 0, nullptr, 0, 0, PP);

    // 9. q = blockdiag(xc, Wq) (fp32 for hgn; transposed-bf16 later for denom)
    tconv_kernel<<<dim3(HS / 32, HS / 64, NH), blk, 0, stream>>>(Wq_w, wt, HS, HS);
    gemm_nt<false, false><<<dim3(HS / 128, BB / 128, NH), blk, 0, stream>>>(
        xc_bf, PP, HS, wt, HS, (long)HS * HS, Wq_b, HS, nullptr, qbuf, HH, HS,
        nullptr, 0, 0, HS);

    // 10. v = blockdiag(xl, Wv)  (before k: frees xl_bf's slot for k)
    tconv_kernel<<<dim3(HS / 32, HS / 64, NH), blk, 0, stream>>>(Wv_w, wt, HS, HS);
    gemm_nt<false, false><<<dim3(HS / 128, BB / 128, NH), blk, 0, stream>>>(
        xl_bf, PP, HS, wt, HS, (long)HS * HS, Wv_b, HS, nullptr, vbuf, HH, HS,
        nullptr, 0, 0, HS);

    // 11. k_raw = blockdiag(xc, Wk) (scaled by 1/16 in gates); overwrites xn/xl_bf slot
    tconv_kernel<<<dim3(HS / 32, HS / 64, NH), blk, 0, stream>>>(Wk_w, wt, HS, HS);
    gemm_nt<false, false><<<dim3(HS / 128, BB / 128, NH), blk, 0, stream>>>(
        xc_bf, PP, HS, wt, HS, (long)HS * HS, Wk_b, HS, nullptr, kbuf, HH, HS,
        nullptr, 0, 0, HS);

    // 12. gates -> c_t, n_t, m_t straight into d_out
    gates_kernel<<<dim3((unsigned)((long)BB * HH / 256)), blk, 0, stream>>>(
        it, ft, m_prev, c_prev, n_prev, kbuf, vbuf, c_out, n_out, m_out);

    // 13. transpose-convert n_t and q for the TN denom GEMM (ft slot is dead)
    tconv_kernel<<<dim3(HH / 32, BB / 64, 1), blk, 0, stream>>>(n_out, nT_bf, BB, HH);
    tconv_kernel<<<dim3(HH / 32, BB / 64, 1), blk, 0, stream>>>(qbuf, qT_bf, BB, HH);

    // 14. denom = n_t^T @ q  [H,H]  (it slot is dead)
    gemm_nt<false, false><<<dim3(HH / 128, HH / 128, 1), blk, 0, stream>>>(
        nT_bf, BB, 0, qT_bf, BB, 0, nullptr, 0, nullptr, den, HH, 0,
        nullptr, 0, 0, BB);

    // 15. h_t, GroupNorm, s = (gn + x_skip) * silu(x_right)  (s_bf over dead v)
    hgn_kernel<<<dim3(BB * NH), blk, 0, stream>>>(
        opre, c_out, qbuf, den, xs, xr, gn_g, gn_b, h_out, s_bf);

    // 16. out = s @ W_down + b_down + x
    tconv_kernel<<<dim3(DD / 32, HH / 64, 1), blk, 0, stream>>>(W_down, wt, HH, DD);
    gemm_nt<false, true><<<dim3(DD / 128, BB / 128, 1), blk, 0, stream>>>(
        s_bf, HH, 0, wt, HH, 0, b_down, 0, x, out0, DD, 0, nullptr, 0, 0, HH);
}

// Round 2
// 2016.988 us; speedup vs baseline: 2.6872x; 1.2481x over previous
//
#include <hip/hip_runtime.h>
#include <math.h>

// mLSTM block, MI355X round 2: 256x256 8-phase-style GEMM (counted vmcnt,
// swizzled LDS, setprio), per guide §5 template / T2+T3+T4+T5.
constexpr int BB = 4096;   // batch
constexpr int DD = 2048;   // input size
constexpr int PP = 4096;   // proj size
constexpr int HH = 4096;   // hidden
constexpr int NH = 16;
constexpr int HS = 256;

using bf16 = __bf16;
typedef __attribute__((ext_vector_type(8))) __bf16 bf16x8;
typedef __attribute__((ext_vector_type(2))) __bf16 bf16x2;
typedef __attribute__((ext_vector_type(4))) float  floatx4;

// ---------------------------------------------------------------- async 16B global->LDS
__device__ __forceinline__ void gl_lds16(const bf16* g, bf16* l) {
    __builtin_amdgcn_global_load_lds(
        (__attribute__((address_space(1))) void*)g,
        (__attribute__((address_space(3))) void*)l,
        16, 0, 0);
}

#define WAITV(n) asm volatile("s_waitcnt vmcnt(" #n ")" ::: "memory")
#define BAR()    asm volatile("s_barrier" ::: "memory")

// ---------------------------------------------------------------- LayerNorm -> bf16
__global__ void ln_kernel(const float* __restrict__ x, const float* __restrict__ g,
                          const float* __restrict__ b, bf16* __restrict__ xn) {
    int row = blockIdx.x;
    int tid = threadIdx.x;
    const float* xr = x + (long)row * DD;
    float v[8];
    float s1 = 0.f, s2 = 0.f;
#pragma unroll
    for (int i = 0; i < 8; ++i) {
        v[i] = xr[tid + 256 * i];
        s1 += v[i]; s2 += v[i] * v[i];
    }
    for (int off = 32; off > 0; off >>= 1) {
        s1 += __shfl_down(s1, off);
        s2 += __shfl_down(s2, off);
    }
    __shared__ float r1[4], r2[4];
    if ((tid & 63) == 0) { r1[tid >> 6] = s1; r2[tid >> 6] = s2; }
    __syncthreads();
    float t1 = r1[0] + r1[1] + r1[2] + r1[3];
    float t2 = r2[0] + r2[1] + r2[2] + r2[3];
    float mu  = t1 * (1.f / DD);
    float var = t2 * (1.f / DD) - mu * mu;
    float inv = rsqrtf(var + 1e-5f);
    bf16* xo = xn + (long)row * DD;
#pragma unroll
    for (int i = 0; i < 8; ++i) {
        int c = tid + 256 * i;
        xo[c] = (bf16)((v[i] - mu) * inv * g[c] + b[c]);
    }
}

// ---------------------------------------------------------------- transpose-convert
// in: [R][C] fp32 row-major  ->  out: [C][R] bf16 row-major.  R%64==0, C%32==0.
__global__ __launch_bounds__(256)
void tconv_kernel(const float* __restrict__ in, bf16* __restrict__ out, int R, int C) {
    __shared__ float t[64][33];
    const long zo = (long)blockIdx.z * (long)R * C;
    in  += zo; out += zo;
    const int c0 = blockIdx.x * 32, r0 = blockIdx.y * 64;
    const int xx = threadIdx.x & 31, yy = threadIdx.x >> 5;   // yy: 0..7
#pragma unroll
    for (int d = 0; d < 64; d += 8)
        t[yy + d][xx] = in[(long)(r0 + yy + d) * C + c0 + xx];
    __syncthreads();
#pragma unroll
    for (int d = 0; d < 32; d += 8) {
        const int cc = c0 + yy + d;
        bf16x2 pk;
        pk.x = (bf16)t[2 * xx + 0][yy + d];
        pk.y = (bf16)t[2 * xx + 1][yy + d];
        *reinterpret_cast<bf16x2*>(&out[(long)cc * R + r0 + 2 * xx]) = pk;
    }
}

// ---------------------------------------------------------------- conv + silu -> bf16
__global__ void conv_silu_kernel(const float* __restrict__ xl, const float* __restrict__ w,
                                 const float* __restrict__ cb, bf16* __restrict__ xc) {
    long i = (long)blockIdx.x * 256 + threadIdx.x;   // over B*P
    int p = (int)(i & (PP - 1));
    const float* base = xl + (i - p);
    float acc = cb[0];
#pragma unroll
    for (int j = 0; j < 4; ++j) {
        int pp = p - 3 + j;
        if (pp >= 0) acc = fmaf(w[j], base[pp], acc);
    }
    xc[i] = (bf16)(acc / (1.f + expf(-acc)));
}

// ---------------------------------------------------------------- gates
__global__ void gates_kernel(const float* __restrict__ it_, const float* __restrict__ ft_,
                             const float* __restrict__ mp, const float* __restrict__ cp,
                             const float* __restrict__ np, const float* __restrict__ kk,
                             const float* __restrict__ vv,
                             float* __restrict__ c_out, float* __restrict__ n_out,
                             float* __restrict__ m_out) {
    long i = (long)blockIdx.x * 256 + threadIdx.x;   // over B*H
    float it = it_[i], ft = ft_[i];
    float fm = ft + mp[i];
    float mt = fmaxf(fm, it);
    float ig = expf(it - mt);
    float fg = expf(fm - mt);
    float ks = kk[i] * 0.0625f;                       // 1/sqrt(HS)
    c_out[i] = fg * cp[i] + ig * (vv[i] * ks);
    n_out[i] = fg * np[i] + ig * ks;
    m_out[i] = mt;
}

// ---------------------------------------------------------------- h_t + GroupNorm + mix
__global__ void hgn_kernel(const float* __restrict__ o_pre, const float* __restrict__ ct,
                           const float* __restrict__ qm, const float* __restrict__ den,
                           const float* __restrict__ xs, const float* __restrict__ xr,
                           const float* __restrict__ gg, const float* __restrict__ gb,
                           float* __restrict__ h_out, bf16* __restrict__ s_out) {
    int blk = blockIdx.x;            // b*NH + head
    int b = blk >> 4, hd = blk & 15;
    int c = threadIdx.x;             // 0..255 == HS
    int gcol = hd * HS + c;
    long idx = (long)b * HH + gcol;
    float o  = 1.f / (1.f + expf(-o_pre[idx]));
    float ht = o * ct[idx] * qm[idx] / fmaxf(fabsf(den[idx]), 1.f);
    h_out[idx] = ht;
    float s1 = ht, s2 = ht * ht;
    for (int off = 32; off > 0; off >>= 1) {
        s1 += __shfl_down(s1, off);
        s2 += __shfl_down(s2, off);
    }
    __shared__ float r1[4], r2[4];
    if ((c & 63) == 0) { r1[c >> 6] = s1; r2[c >> 6] = s2; }
    __syncthreads();
    float t1 = r1[0] + r1[1] + r1[2] + r1[3];
    float t2 = r2[0] + r2[1] + r2[2] + r2[3];
    float mu  = t1 * (1.f / HS);
    float var = t2 * (1.f / HS) - mu * mu;
    float gn  = (ht - mu) * rsqrtf(var + 1e-5f) * gg[gcol] + gb[gcol];
    float xrv = xr[idx];
    float sil = xrv / (1.f + expf(-xrv));
    s_out[idx] = (bf16)((gn + xs[idx]) * sil);
}

// ---------------------------------------------------------------- GEMM 256x256, BK=64
// C[m,n] = sum_k A[m,k]*Bt[n,k] + bias[n] (+res). A:[M,K] bf16, Bt:[N,K] bf16.
// 512 threads = 8 waves (2 wr x 4 wc); per-wave 128x64 output = acc[8][4].
// LDS: per operand, 4 slots of 16KB (256 rows x 32 k-cols), ring over (tile,kslice).
// Swizzle: byte ^= ((row>>1)&3)<<4  (conflict-free quarter-wave b128 reads);
// staged via inverse-swizzled GLOBAL source + linear global_load_lds dest.
// Pipeline: 4 phases/tile {ds_read | stage half of t+1 | MFMA}, vmcnt(4) at
// phases 1,3 only (counted, never 0 in loop), s_barrier per phase.
template<bool WRITE_BF16, bool ADD_RES>
__global__ __launch_bounds__(512, 2)
void gemm256(const bf16* __restrict__ A, int lda, long sAz,
             const bf16* __restrict__ Bt, int ldb, long sBz,
             const float* __restrict__ bias, int sbz,
             const float* __restrict__ res,
             float* __restrict__ C, int ldc, long sCz,
             bf16* __restrict__ Cb, int ldcb, long sCbz,
             int K) {
    __shared__ bf16 smA[2][2][8192];   // [ring][kslice][256*32] = 64KB
    __shared__ bf16 smB[2][2][8192];   // 64KB

    const int tid  = threadIdx.x;
    const int wave = tid >> 6, lane = tid & 63;

    // XCD-rectangle swizzle for 16x16 grids (8 rectangles of 4y x 8x)
    int bx = blockIdx.x, by = blockIdx.y;
    if (gridDim.x == 16 && gridDim.y == 16) {
        int bid = by * 16 + bx;
        int r = bid & 7, i = bid >> 3;
        by = (r >> 1) * 4 + (i >> 3);
        bx = (r & 1) * 8 + (i & 7);
    }
    const int m0 = by * 256, n0 = bx * 256, z = blockIdx.z;
    A  += (long)z * sAz;
    Bt += (long)z * sBz;
    C  += (long)z * sCz;
    if (bias) bias += (long)z * sbz;
    if (WRITE_BF16) Cb += (long)z * sCbz;

    // staging: thread t covers row (s*128 + t>>2), 16B chunk u=(t&3); the data
    // it loads is logical chunk u' = u ^ ((row>>1)&3)  (inverse swizzle).
    const int srow = tid >> 2;
    const int scol = ((tid & 3) ^ ((tid >> 3) & 3)) * 8;
    const bf16* pA = A  + (long)(m0 + srow) * lda + scol;
    const bf16* pB = Bt + (long)(n0 + srow) * ldb + scol;

#define STAGE_A(dd, kkk, kcol) do { \
    const bf16* _s = pA + (kcol) + (kkk) * 32; \
    gl_lds16(_s,                   &smA[dd][kkk][wave * 512]); \
    gl_lds16(_s + 128 * (long)lda, &smA[dd][kkk][4096 + wave * 512]); } while (0)
#define STAGE_B(dd, kkk, kcol) do { \
    const bf16* _s = pB + (kcol) + (kkk) * 32; \
    gl_lds16(_s,                   &smB[dd][kkk][wave * 512]); \
    gl_lds16(_s + 128 * (long)ldb, &smB[dd][kkk][4096 + wave * 512]); } while (0)
#define LD8(base, off) (*reinterpret_cast<const bf16x8*>((const char*)(base) + (off)))

    const int wr = wave >> 2, wc = wave & 3;
    const int lr = lane & 15, qd = lane >> 4;
    const int xorv = ((lr >> 1) & 3) << 4;
    // frag byte offsets (row*64 + swizzled 16B chunk)
    const int aoff = (wr * 128 + lr) * 64 + ((qd * 16) ^ xorv);   // +i*1024, +4096 for i>=4
    const int boff = (wc * 64  + lr) * 64 + ((qd * 16) ^ xorv);   // +j*1024

    floatx4 acc[8][4] = {};
    const int nt = K >> 6;

    // prologue: stage tile 0 (both k-slices)
    STAGE_A(0, 0, 0); STAGE_B(0, 0, 0); STAGE_A(0, 1, 0); STAGE_B(0, 1, 0);
    WAITV(4);                                  // A-K0, B-K0 landed; K1 in flight
    BAR();

    for (int t = 0; t < nt; ++t) {
        const int d = t & 1, e = d ^ 1;
        const int kn = (t + 1 < nt) ? (t + 1) * 64 : 0;   // clamp: dummy loads on last tile
        const char* A0p = (const char*)&smA[d][0][0];
        const char* A1p = (const char*)&smA[d][1][0];
        const char* B0p = (const char*)&smB[d][0][0];
        const char* B1p = (const char*)&smB[d][1][0];
        bf16x8 af[4], bv[4];

        // ---- phase 0: kslice 0, acc rows 0-3
#pragma unroll
        for (int i = 0; i < 4; ++i) af[i] = LD8(A0p, aoff + i * 1024);
#pragma unroll
        for (int j = 0; j < 4; ++j) bv[j] = LD8(B0p, boff + j * 1024);
        STAGE_A(e, 0, kn);
        __builtin_amdgcn_s_setprio(1);
#pragma unroll
        for (int i = 0; i < 4; ++i)
#pragma unroll
            for (int j = 0; j < 4; ++j)
                acc[i][j] = __builtin_amdgcn_mfma_f32_16x16x32_bf16(af[i], bv[j], acc[i][j], 0, 0, 0);
        __builtin_amdgcn_s_setprio(0);
        BAR();

        // ---- phase 1: kslice 0, acc rows 4-7 (reuse bv)
#pragma unroll
        for (int i = 0; i < 4; ++i) af[i] = LD8(A0p, aoff + 4096 + i * 1024);
        STAGE_B(e, 0, kn);
        __builtin_amdgcn_s_setprio(1);
#pragma unroll
        for (int i = 0; i < 4; ++i)
#pragma unroll
            for (int j = 0; j < 4; ++j)
                acc[4 + i][j] = __builtin_amdgcn_mfma_f32_16x16x32_bf16(af[i], bv[j], acc[4 + i][j], 0, 0, 0);
        __builtin_amdgcn_s_setprio(0);
        WAITV(4);                              // tile t's K1 halves landed
        BAR();

        // ---- phase 2: kslice 1, acc rows 0-3
#pragma unroll
        for (int i = 0; i < 4; ++i) af[i] = LD8(A1p, aoff + i * 1024);
#pragma unroll
        for (int j = 0; j < 4; ++j) bv[j] = LD8(B1p, boff + j * 1024);
        STAGE_A(e, 1, kn);
        __builtin_amdgcn_s_setprio(1);
#pragma unroll
        for (int i = 0; i < 4; ++i)
#pragma unroll
            for (int j = 0; j < 4; ++j)
                acc[i][j] = __builtin_amdgcn_mfma_f32_16x16x32_bf16(af[i], bv[j], acc[i][j], 0, 0, 0);
        __builtin_amdgcn_s_setprio(0);
        BAR();

        // ---- phase 3: kslice 1, acc rows 4-7 (reuse bv)
#pragma unroll
        for (int i = 0; i < 4; ++i) af[i] = LD8(A1p, aoff + 4096 + i * 1024);
        STAGE_B(e, 1, kn);
        __builtin_amdgcn_s_setprio(1);
#pragma unroll
        for (int i = 0; i < 4; ++i)
#pragma unroll
            for (int j = 0; j < 4; ++j)
                acc[4 + i][j] = __builtin_amdgcn_mfma_f32_16x16x32_bf16(af[i], bv[j], acc[4 + i][j], 0, 0, 0);
        __builtin_amdgcn_s_setprio(0);
        WAITV(4);                              // tile t+1's K0 halves landed
        BAR();
    }

    // epilogue: D row = qd*4 + r, col = lr (verified m89 layout)
#pragma unroll
    for (int i = 0; i < 8; ++i) {
        const int rowb = m0 + wr * 128 + i * 16 + qd * 4;
#pragma unroll
        for (int j = 0; j < 4; ++j) {
            const int col = n0 + wc * 64 + j * 16 + lr;
            const float bi = bias ? bias[col] : 0.f;
#pragma unroll
            for (int r = 0; r < 4; ++r) {
                const long gi = (long)(rowb + r) * ldc + col;
                float v0 = acc[i][j][r] + bi;
                if (ADD_RES) v0 += res[gi];
                C[gi] = v0;
                if (WRITE_BF16) Cb[(long)(rowb + r) * ldcb + col] = (bf16)v0;
            }
        }
    }
#undef STAGE_A
#undef STAGE_B
#undef LD8
}

// ---------------------------------------------------------------- launch
extern "C" void kernel_launch(void* const* d_in, const int* in_sizes, int n_in,
                              void* d_out, int out_size, void* d_ws, size_t ws_size,
                              hipStream_t stream) {
    const float* x      = (const float*)d_in[0];
    // d_in[1] = h_prev (unused by the reference math)
    const float* c_prev = (const float*)d_in[2];
    const float* n_prev = (const float*)d_in[3];
    const float* m_prev = (const float*)d_in[4];
    const float* ln_g   = (const float*)d_in[5];
    const float* ln_b   = (const float*)d_in[6];
    const float* W_upL  = (const float*)d_in[7];
    const float* b_upL  = (const float*)d_in[8];
    const float* W_upR  = (const float*)d_in[9];
    const float* b_upR  = (const float*)d_in[10];
    const float* conv_w = (const float*)d_in[11];
    const float* conv_b = (const float*)d_in[12];
    const float* W_skip = (const float*)d_in[13];
    const float* b_skip = (const float*)d_in[14];
    const float* Wq_w   = (const float*)d_in[15];
    const float* Wq_b   = (const float*)d_in[16];
    const float* Wk_w   = (const float*)d_in[17];
    const float* Wk_b   = (const float*)d_in[18];
    const float* Wv_w   = (const float*)d_in[19];
    const float* Wv_b   = (const float*)d_in[20];
    const float* Wi_w   = (const float*)d_in[21];
    const float* Wi_b   = (const float*)d_in[22];
    const float* Wf_w   = (const float*)d_in[23];
    const float* Wf_b   = (const float*)d_in[24];
    const float* Wo_w   = (const float*)d_in[25];
    const float* Wo_b   = (const float*)d_in[26];
    const float* gn_g   = (const float*)d_in[27];
    const float* gn_b   = (const float*)d_in[28];
    const float* W_down = (const float*)d_in[29];
    const float* b_down = (const float*)d_in[30];

    float* out0  = (float*)d_out;                       // [B, D]
    float* h_out = out0  + (long)BB * DD;               // [B, H]
    float* c_out = h_out + (long)BB * HH;
    float* n_out = c_out + (long)BB * HH;
    float* m_out = n_out + (long)BB * HH;

    // Workspace: 9 fp32 slots of B*H floats (64 MiB) = 576 MiB, lifetime-aliased.
    float* ws = (float*)d_ws;
    const long SLOT = (long)BB * HH;                    // 16,777,216 floats
    float* s0 = ws + 0 * SLOT;   // xr fp32                         [live -> hgn]
    float* s1 = ws + 1 * SLOT;   // xs fp32                         [-> hgn]
    float* s2 = ws + 2 * SLOT;   // it fp32 [-> gates], then denom  [-> hgn]
    float* s3 = ws + 3 * SLOT;   // ft fp32 [-> gates], then nT_bf | qT_bf
    float* s4 = ws + 4 * SLOT;   // opre fp32                       [-> hgn]
    float* s5 = ws + 5 * SLOT;   // q fp32                          [-> hgn]
    float* s6 = ws + 6 * SLOT;   // xn_bf + xl_bf, then k fp32      [-> gates]
    float* s7 = ws + 7 * SLOT;   // xl fp32 [-> conv], then v fp32 [-> gates], then s_bf
    float* s8 = ws + 8 * SLOT;   // wt scratch (32MB) + xc_bf (32MB)

    float* xr   = s0;
    float* xs   = s1;
    float* it   = s2;
    float* den  = s2;
    float* ft   = s3;
    float* opre = s4;
    float* qbuf = s5;
    float* kbuf = s6;
    float* xl   = s7;
    float* vbuf = s7;

    bf16* xn_bf = (bf16*)s6;                 // 16 MB  [ln .. upR]
    bf16* xl_bf = (bf16*)(s6 + SLOT / 4);    // 32 MB  [upL .. v-gemm]
    bf16* nT_bf = (bf16*)s3;                 // 32 MB  [after gates]
    bf16* qT_bf = (bf16*)(s3 + SLOT / 2);    // 32 MB
    bf16* wt    = (bf16*)s8;                 // 32 MB weight scratch (per-GEMM)
    bf16* xc_bf = (bf16*)(s8 + SLOT / 2);    // 32 MB  [conv .. k-gemm]
    bf16* s_bf  = (bf16*)s7;                 // 32 MB  [hgn .. down]

    dim3 blk(256);
    dim3 gblk(512);

    // 1. LayerNorm -> bf16
    ln_kernel<<<BB, blk, 0, stream>>>(x, ln_g, ln_b, xn_bf);

    // 2. x_left = xn @ W_upL + b_upL  (fp32 for conv, bf16 for v/o GEMMs)
    tconv_kernel<<<dim3(PP / 32, DD / 64, 1), blk, 0, stream>>>(W_upL, wt, DD, PP);
    gemm256<true, false><<<dim3(PP / 256, BB / 256, 1), gblk, 0, stream>>>(
        xn_bf, DD, 0, wt, DD, 0, b_upL, 0, nullptr, xl, PP, 0, xl_bf, PP, 0, DD);

    // 3. x_right = xn @ W_upR + b_upR (fp32, consumed elementwise in hgn)
    tconv_kernel<<<dim3(HH / 32, DD / 64, 1), blk, 0, stream>>>(W_upR, wt, DD, HH);
    gemm256<false, false><<<dim3(HH / 256, BB / 256, 1), gblk, 0, stream>>>(
        xn_bf, DD, 0, wt, DD, 0, b_upR, 0, nullptr, xr, HH, 0, nullptr, 0, 0, DD);

    // 4. causal conv(4) + silu -> bf16
    conv_silu_kernel<<<dim3((unsigned)((long)BB * PP / 256)), blk, 0, stream>>>(
        xl, conv_w, conv_b, xc_bf);

    // 5. x_skip = xc @ W_skip
    tconv_kernel<<<dim3(HH / 32, PP / 64, 1), blk, 0, stream>>>(W_skip, wt, PP, HH);
    gemm256<false, false><<<dim3(HH / 256, BB / 256, 1), gblk, 0, stream>>>(
        xc_bf, PP, 0, wt, PP, 0, b_skip, 0, nullptr, xs, HH, 0, nullptr, 0, 0, PP);

    // 6. i_tilde = xc @ Wi
    tconv_kernel<<<dim3(HH / 32, PP / 64, 1), blk, 0, stream>>>(Wi_w, wt, PP, HH);
    gemm256<false, false><<<dim3(HH / 256, BB / 256, 1), gblk, 0, stream>>>(
        xc_bf, PP, 0, wt, PP, 0, Wi_b, 0, nullptr, it, HH, 0, nullptr, 0, 0, PP);

    // 7. f_tilde = xc @ Wf
    tconv_kernel<<<dim3(HH / 32, PP / 64, 1), blk, 0, stream>>>(Wf_w, wt, PP, HH);
    gemm256<false, false><<<dim3(HH / 256, BB / 256, 1), gblk, 0, stream>>>(
        xc_bf, PP, 0, wt, PP, 0, Wf_b, 0, nullptr, ft, HH, 0, nullptr, 0, 0, PP);

    // 8. o_pre = xl @ Wo
    tconv_kernel<<<dim3(HH / 32, PP / 64, 1), blk, 0, stream>>>(Wo_w, wt, PP, HH);
    gemm256<false, false><<<dim3(HH / 256, BB / 256, 1), gblk, 0, stream>>>(
        xl_bf, PP, 0, wt, PP, 0, Wo_b, 0, nullptr, opre, HH, 0, nullptr, 0, 0, PP);

    // 9. q = blockdiag(xc, Wq) (fp32 for hgn; transposed-bf16 later for denom)
    tconv_kernel<<<dim3(HS / 32, HS / 64, NH), blk, 0, stream>>>(Wq_w, wt, HS, HS);
    gemm256<false, false><<<dim3(1, BB / 256, NH), gblk, 0, stream>>>(
        xc_bf, PP, HS, wt, HS, (long)HS * HS, Wq_b, HS, nullptr, qbuf, HH, HS,
        nullptr, 0, 0, HS);

    // 10. v = blockdiag(xl, Wv)  (before k: frees xl_bf's slot for k)
    tconv_kernel<<<dim3(HS / 32, HS / 64, NH), blk, 0, stream>>>(Wv_w, wt, HS, HS);
    gemm256<false, false><<<dim3(1, BB / 256, NH), gblk, 0, stream>>>(
        xl_bf, PP, HS, wt, HS, (long)HS * HS, Wv_b, HS, nullptr, vbuf, HH, HS,
        nullptr, 0, 0, HS);

    // 11. k_raw = blockdiag(xc, Wk) (scaled by 1/16 in gates); overwrites xn/xl_bf slot
    tconv_kernel<<<dim3(HS / 32, HS / 64, NH), blk, 0, stream>>>(Wk_w, wt, HS, HS);
    gemm256<false, false><<<dim3(1, BB / 256, NH), gblk, 0, stream>>>(
        xc_bf, PP, HS, wt, HS, (long)HS * HS, Wk_b, HS, nullptr, kbuf, HH, HS,
        nullptr, 0, 0, HS);

    // 12. gates -> c_t, n_t, m_t straight into d_out
    gates_kernel<<<dim3((unsigned)((long)BB * HH / 256)), blk, 0, stream>>>(
        it, ft, m_prev, c_prev, n_prev, kbuf, vbuf, c_out, n_out, m_out);

    // 13. transpose-convert n_t and q for the TN denom GEMM (ft slot is dead)
    tconv_kernel<<<dim3(HH / 32, BB / 64, 1), blk, 0, stream>>>(n_out, nT_bf, BB, HH);
    tconv_kernel<<<dim3(HH / 32, BB / 64, 1), blk, 0, stream>>>(qbuf, qT_bf, BB, HH);

    // 14. denom = n_t^T @ q  [H,H]  (it slot is dead)
    gemm256<false, false><<<dim3(HH / 256, HH / 256, 1), gblk, 0, stream>>>(
        nT_bf, BB, 0, qT_bf, BB, 0, nullptr, 0, nullptr, den, HH, 0,
        nullptr, 0, 0, BB);

    // 15. h_t, GroupNorm, s = (gn + x_skip) * silu(x_right)  (s_bf over dead v)
    hgn_kernel<<<dim3(BB * NH), blk, 0, stream>>>(
        opre, c_out, qbuf, den, xs, xr, gn_g, gn_b, h_out, s_bf);

    // 16. out = s @ W_down + b_down + x
    tconv_kernel<<<dim3(DD / 32, HH / 64, 1), blk, 0, stream>>>(W_down, wt, HH, DD);
    gemm256<false, true><<<dim3(DD / 256, BB / 256, 1), gblk, 0, stream>>>(
        s_bf, HH, 0, wt, HH, 0, b_down, 0, x, out0, DD, 0, nullptr, 0, 0, HH);
}